// Round 10
// baseline (1332.123 us; speedup 1.0000x reference)
//
#include <hip/hip_runtime.h>

#define BATCH  4096
#define TSTEPS 64
#define FDIM   128
#define HDIM   256
#define ODIM   64
#define MROWS  64
#define NBLK   64     // BATCH / MROWS
#define NTHR   1024   // 16 waves; launch_bounds(,4) -> 128-reg budget, 1 block/CU

typedef __attribute__((ext_vector_type(8))) short  short8;
typedef __attribute__((ext_vector_type(4))) float  floatx4;

#define MFMA(a,b,c) __builtin_amdgcn_mfma_f32_16x16x32_bf16((a),(b),(c),0,0,0)

__device__ __forceinline__ unsigned short f2bf(float f){
  unsigned u = __builtin_bit_cast(unsigned, f);
  u += 0x7FFFu + ((u >> 16) & 1u);           // RTNE
  return (unsigned short)(u >> 16);
}
__device__ __forceinline__ float sigm(float x){
  return __builtin_amdgcn_rcpf(1.f + __expf(-x));
}
__device__ __forceinline__ float tanh_f(float x){
  return 2.f * __builtin_amdgcn_rcpf(1.f + __expf(-2.f * x)) - 1.f;
}

// ---------------- phase 0: fragment weights into d_ws ----------
// warr[((gf*12 + kf)*64 + lane)*8 + i]; gf 0..47, kf 0..7 = w_hh, 8..11 = w_ih
// element = W[16*gf + (lane&15)][32*kf + 8*(lane>>4) + i]  (A-frag, row=lane&15)
__global__ void prep_weights(const float* __restrict__ w_ih,
                             const float* __restrict__ w_hh,
                             unsigned short* __restrict__ warr){
  int idx = blockIdx.x * 256 + threadIdx.x;
  if (idx >= 48*12*64) return;
  int gf   = idx / 768;
  int rr   = idx - gf*768;
  int kf   = rr >> 6;
  int lane = rr & 63;
  int lo = lane & 15, hi = lane >> 4;
  const float* src = (kf < 8) ? (w_hh + (size_t)(16*gf + lo)*HDIM + 32*kf     + 8*hi)
                              : (w_ih + (size_t)(16*gf + lo)*FDIM + 32*(kf-8) + 8*hi);
  unsigned short* dst = warr + (size_t)idx * 8;
  #pragma unroll
  for (int i = 0; i < 8; ++i) dst[i] = f2bf(src[i]);
}

// ---- LDS swizzle (bank-quad = (col>>4) ^ (row&7); conflict-minimal)
__device__ __forceinline__ short8 ldsH(const unsigned char* sm, int row, int col){
  return *(const short8*)(sm + row*512 + (col ^ ((row & 7) << 4)));
}
__device__ __forceinline__ short8 ldsX(const unsigned char* sm, int row, int col){
  return *(const short8*)(sm + row*256 + (col ^ ((row & 7) << 4)));
}

// ---------------- main fused kernel ----------------
template<int KOFF>
__device__ __forceinline__ void gru_body(
    const float* __restrict__ feat, const unsigned short* __restrict__ warr,
    const float* __restrict__ b_ih, const float* __restrict__ b_hh,
    const float* __restrict__ w_pi, const float* __restrict__ b_pi,
    const float* __restrict__ w_vf, const float* __restrict__ b_vf,
    float* __restrict__ out,
    unsigned char* sm_h, unsigned char* sm_x, float* biasL){

  const int tid  = threadIdx.x;
  const int wv   = tid >> 6;              // 0..15 -> owns gate-cols [16wv,16wv+16) of each gate
  const int lane = tid & 63;
  const int lo   = lane & 15, hi = lane >> 4;
  const int row0 = blockIdx.x * MROWS;
  const int cb   = 16*wv + 4*hi;          // gate/h col base for this lane
  const int gfr  = wv, gfz = 16 + wv, gfn = 32 + wv;

  const unsigned short* wl = warr + lane*8;

  // ---- one-time: bias -> LDS
  if      (tid < 512) biasL[tid] = b_ih[tid] + b_hh[tid];   // r,z combined
  else if (tid < 768) biasL[tid] = b_ih[tid];               // xn
  else                biasL[tid] = b_hh[tid - 256];         // hn

  // ---- zero sm_h (2048 int4)
  #pragma unroll
  for (int i = 0; i < 2; ++i) ((int4*)sm_h)[tid + i*NTHR] = make_int4(0,0,0,0);
  // ---- stage x[0]: 64 rows x 32 chunks = 2048 -> 2 per thread
  #pragma unroll
  for (int i = 0; i < 2; ++i){
    int cid = tid + i*NTHR;
    int r   = cid >> 5;
    int c4  = cid & 31;
    floatx4 v = __builtin_nontemporal_load(
        (const floatx4*)(feat + (size_t)(row0 + r)*(TSTEPS*FDIM)) + c4);
    uint2 pk;
    pk.x = (unsigned)f2bf(v[0]) | ((unsigned)f2bf(v[1]) << 16);
    pk.y = (unsigned)f2bf(v[2]) | ((unsigned)f2bf(v[3]) << 16);
    *(uint2*)(sm_x + r*256 + ((c4*8) ^ ((r & 7) << 4))) = pk;
  }

  float hold[4][4];
  #pragma unroll
  for (int m = 0; m < 4; ++m)
    #pragma unroll
    for (int j = 0; j < 4; ++j) hold[m][j] = 0.f;

  __syncthreads();

  const int xr  = tid >> 5;      // rows 0..31 (thread tid) and 32..63 (tid+1024)
  const int xc4 = tid & 31;

  #pragma unroll 1
  for (int t = 0; t < TSTEPS; ++t){
    // ---- prefetch x[t+1] (2 chunks/thread, written after MFMA barrier)
    int tn = (t < TSTEPS-1) ? (t+1) : (TSTEPS-1);
    floatx4 xf0 = __builtin_nontemporal_load(
        (const floatx4*)(feat + (size_t)(row0 + xr)*(TSTEPS*FDIM) + (size_t)tn*FDIM) + xc4);
    floatx4 xf1 = __builtin_nontemporal_load(
        (const floatx4*)(feat + (size_t)(row0 + 32 + xr)*(TSTEPS*FDIM) + (size_t)tn*FDIM) + xc4);

    // ---- acc init from LDS bias
    floatx4 ar[4], az[4], anh[4], anx[4];
    {
      floatx4 vr = *(const floatx4*)(biasL + cb);
      floatx4 vz = *(const floatx4*)(biasL + 256 + cb);
      floatx4 vx = *(const floatx4*)(biasL + 512 + cb);
      floatx4 vh = *(const floatx4*)(biasL + 768 + cb);
      #pragma unroll
      for (int m = 0; m < 4; ++m){ ar[m] = vr; az[m] = vz; anh[m] = vh; anx[m] = vx; }
    }

    // ---- 12 rounds, rolling depth-1 A prefetch; 4 B-frags (64 rows) per round
    constexpr int K0 = KOFF % 12;
    short8 a0c = *(const short8*)(wl + (gfr*12 + K0)*512);
    short8 a1c = *(const short8*)(wl + (gfz*12 + K0)*512);
    short8 a2c = *(const short8*)(wl + (gfn*12 + K0)*512);
    #pragma unroll
    for (int g = 0; g < 12; ++g){
      const int kf = (g + KOFF) % 12;
      short8 a0n, a1n, a2n;
      if (g < 11){
        const int k2 = (g + 1 + KOFF) % 12;
        a0n = *(const short8*)(wl + (gfr*12 + k2)*512);
        a1n = *(const short8*)(wl + (gfz*12 + k2)*512);
        a2n = *(const short8*)(wl + (gfn*12 + k2)*512);
      }
      #pragma unroll
      for (int m = 0; m < 4; ++m){
        short8 b = (kf < 8) ? ldsH(sm_h, 16*m + lo, kf*64 + hi*16)
                            : ldsX(sm_x, 16*m + lo, (kf-8)*64 + hi*16);
        ar[m] = MFMA(a0c, b, ar[m]);
        az[m] = MFMA(a1c, b, az[m]);
        if (kf < 8) anh[m] = MFMA(a2c, b, anh[m]);
        else        anx[m] = MFMA(a2c, b, anx[m]);
      }
      a0c = a0n; a1c = a1n; a2c = a2n;
    }
    __syncthreads();   // all sm_h / sm_x reads of this step done

    // ---- write x[t+1]
    if (t < TSTEPS-1){
      uint2 pk;
      pk.x = (unsigned)f2bf(xf0[0]) | ((unsigned)f2bf(xf0[1]) << 16);
      pk.y = (unsigned)f2bf(xf0[2]) | ((unsigned)f2bf(xf0[3]) << 16);
      *(uint2*)(sm_x + xr*256 + ((xc4*8) ^ ((xr & 7) << 4))) = pk;
      int r2 = 32 + xr;
      pk.x = (unsigned)f2bf(xf1[0]) | ((unsigned)f2bf(xf1[1]) << 16);
      pk.y = (unsigned)f2bf(xf1[2]) | ((unsigned)f2bf(xf1[3]) << 16);
      *(uint2*)(sm_x + r2*256 + ((xc4*8) ^ ((r2 & 7) << 4))) = pk;
    }

    // ---- lane-local gate math; write h_new (bf16, swizzled, 8B packed)
    #pragma unroll
    for (int m = 0; m < 4; ++m){
      int row = 16*m + lo;
      unsigned q[4];
      #pragma unroll
      for (int j = 0; j < 4; ++j){
        float r  = sigm(ar[m][j]);
        float z  = sigm(az[m][j]);
        float n  = tanh_f(anx[m][j] + r*anh[m][j]);
        float hv = (1.f - z)*n + z*hold[m][j];
        hold[m][j] = hv;
        q[j] = f2bf(hv);
      }
      uint2 pk; pk.x = q[0] | (q[1] << 16); pk.y = q[2] | (q[3] << 16);
      *(uint2*)(sm_h + row*512 + ((cb*2) ^ ((row & 7) << 4))) = pk;
    }
    __syncthreads();   // h[t+1], x[t+1] visible
  }

  // ---- epilogue: leaky(h_last) -> sm_h (bf16)
  #pragma unroll
  for (int m = 0; m < 4; ++m){
    int row = 16*m + lo;
    unsigned q[4];
    #pragma unroll
    for (int j = 0; j < 4; ++j){
      float v = hold[m][j];
      v = (v >= 0.f) ? v : 0.01f*v;
      q[j] = f2bf(v);
    }
    uint2 pk; pk.x = q[0] | (q[1] << 16); pk.y = q[2] | (q[3] << 16);
    *(uint2*)(sm_h + row*512 + ((cb*2) ^ ((row & 7) << 4))) = pk;
  }
  __syncthreads();

  // ---- heads: 16 waves = 2 heads x 4 out-frags x 2 row-halves
  const int head = wv >> 3;            // 0 = pi, 1 = vf
  const int sub  = wv & 7;
  const int mfo  = sub >> 1;           // out-col frag 0..3
  const int rh   = sub & 1;            // row half: frags {2rh, 2rh+1}
  const float* wh = head ? w_vf : w_pi;
  const float* bh = head ? b_vf : b_pi;
  floatx4 acc0 = {0.f,0.f,0.f,0.f}, acc1 = {0.f,0.f,0.f,0.f};
  #pragma unroll
  for (int kf = 0; kf < 8; ++kf){
    const float* ap = wh + (size_t)(16*mfo + lo)*HDIM + 32*kf + 8*hi;
    floatx4 av0 = *(const floatx4*)ap;
    floatx4 av1 = *(const floatx4*)(ap + 4);
    short8 a;
    a[0]=(short)f2bf(av0[0]); a[1]=(short)f2bf(av0[1]); a[2]=(short)f2bf(av0[2]); a[3]=(short)f2bf(av0[3]);
    a[4]=(short)f2bf(av1[0]); a[5]=(short)f2bf(av1[1]); a[6]=(short)f2bf(av1[2]); a[7]=(short)f2bf(av1[3]);
    short8 b0 = ldsH(sm_h, 16*(2*rh)     + lo, kf*64 + hi*16);
    short8 b1 = ldsH(sm_h, 16*(2*rh + 1) + lo, kf*64 + hi*16);
    acc0 = MFMA(a, b0, acc0);
    acc1 = MFMA(a, b1, acc1);
  }
  const size_t outoff = (size_t)head * ((size_t)BATCH * ODIM);
  #pragma unroll
  for (int b = 0; b < 2; ++b){
    floatx4 ac = b ? acc1 : acc0;
    int grow = row0 + 16*(2*rh + b) + lo;
    #pragma unroll
    for (int j = 0; j < 4; ++j){
      int od = 16*mfo + 4*hi + j;
      float v = ac[j] + bh[od];
      v = (v >= 0.f) ? v : 0.01f*v;
      out[outoff + (size_t)grow*ODIM + od] = v;
    }
  }
}

__global__ __launch_bounds__(NTHR, 4)
void gru_fused(const float* __restrict__ feat, const unsigned short* __restrict__ warr,
               const float* __restrict__ b_ih, const float* __restrict__ b_hh,
               const float* __restrict__ w_pi, const float* __restrict__ b_pi,
               const float* __restrict__ w_vf, const float* __restrict__ b_vf,
               float* __restrict__ out){
  __shared__ __align__(16) unsigned char sm_h[MROWS*512];   // 32 KB
  __shared__ __align__(16) unsigned char sm_x[MROWS*256];   // 16 KB
  __shared__ __align__(16) float biasL[1024];               // 4 KB
  if (blockIdx.x & 1)
    gru_body<6>(feat, warr, b_ih, b_hh, w_pi, b_pi, w_vf, b_vf, out, sm_h, sm_x, biasL);
  else
    gru_body<0>(feat, warr, b_ih, b_hh, w_pi, b_pi, w_vf, b_vf, out, sm_h, sm_x, biasL);
}

extern "C" void kernel_launch(void* const* d_in, const int* in_sizes, int n_in,
                              void* d_out, int out_size, void* d_ws, size_t ws_size,
                              hipStream_t stream){
  const float* feat = (const float*)d_in[0];
  const float* w_ih = (const float*)d_in[1];
  const float* w_hh = (const float*)d_in[2];
  const float* b_ih = (const float*)d_in[3];
  const float* b_hh = (const float*)d_in[4];
  const float* w_pi = (const float*)d_in[5];
  const float* b_pi = (const float*)d_in[6];
  const float* w_vf = (const float*)d_in[7];
  const float* b_vf = (const float*)d_in[8];

  unsigned short* warr = (unsigned short*)d_ws;   // 589824 B

  prep_weights<<<144, 256, 0, stream>>>(w_ih, w_hh, warr);
  gru_fused<<<NBLK, NTHR, 0, stream>>>(feat, warr, b_ih, b_hh,
                                       w_pi, b_pi, w_vf, b_vf, (float*)d_out);
}

// Round 11
// 1280.587 us; speedup vs baseline: 1.0402x; 1.0402x over previous
//
#include <hip/hip_runtime.h>

#define BATCH  4096
#define TSTEPS 64
#define FDIM   128
#define HDIM   256
#define ODIM   64
#define MROWS  32
#define NBLK   128    // BATCH / MROWS
#define NTHR   1024   // 16 waves, 1 block/CU (160KB LDS), 4 waves/SIMD

#define SMEM_BYTES 163840   // sm_h 16K + ring: 16 waves x 3 slots x 3KB = 144K

typedef __attribute__((ext_vector_type(8))) short  short8;
typedef __attribute__((ext_vector_type(4))) float  floatx4;

#define MFMA(a,b,c) __builtin_amdgcn_mfma_f32_16x16x32_bf16((a),(b),(c),0,0,0)

__device__ __forceinline__ unsigned short f2bf(float f){
  unsigned u = __builtin_bit_cast(unsigned, f);
  u += 0x7FFFu + ((u >> 16) & 1u);           // RTNE
  return (unsigned short)(u >> 16);
}
__device__ __forceinline__ float sigm(float x){
  return __builtin_amdgcn_rcpf(1.f + __expf(-x));
}
__device__ __forceinline__ float tanh_f(float x){
  return 2.f * __builtin_amdgcn_rcpf(1.f + __expf(-2.f * x)) - 1.f;
}

// async 16B/lane global -> LDS (LDS dest = wave-uniform base + lane*16)
__device__ __forceinline__ void dma16(const void* g, void* l){
  __builtin_amdgcn_global_load_lds(
      (const __attribute__((address_space(1))) unsigned int*)g,
      (__attribute__((address_space(3))) unsigned int*)l, 16, 0, 0);
}

// ---------------- phase 0: fragment weights into d_ws ----------
// warr[((gf*12 + kf)*64 + lane)*8 + i]; gf 0..47, kf 0..7 = w_hh, 8..11 = w_ih
// element = W[16*gf + (lane&15)][32*kf + 8*(lane>>4) + i]  (A-frag, row=lane&15)
__global__ void prep_weights(const float* __restrict__ w_ih,
                             const float* __restrict__ w_hh,
                             unsigned short* __restrict__ warr){
  int idx = blockIdx.x * 256 + threadIdx.x;
  if (idx >= 48*12*64) return;
  int gf   = idx / 768;
  int rr   = idx - gf*768;
  int kf   = rr >> 6;
  int lane = rr & 63;
  int lo = lane & 15, hi = lane >> 4;
  const float* src = (kf < 8) ? (w_hh + (size_t)(16*gf + lo)*HDIM + 32*kf     + 8*hi)
                              : (w_ih + (size_t)(16*gf + lo)*FDIM + 32*(kf-8) + 8*hi);
  unsigned short* dst = warr + (size_t)idx * 8;
  #pragma unroll
  for (int i = 0; i < 8; ++i) dst[i] = f2bf(src[i]);
}

// ---- LDS swizzle (bank-quad = (col>>4) ^ (row&7); conflict-minimal)
__device__ __forceinline__ short8 ldsH(const unsigned char* sm, int row, int col){
  return *(const short8*)(sm + row*512 + (col ^ ((row & 7) << 4)));
}

__device__ __forceinline__ short8 cvt8(floatx4 a, floatx4 b){
  union { unsigned u[4]; short8 s; } r;
  r.u[0] = (unsigned)f2bf(a[0]) | ((unsigned)f2bf(a[1]) << 16);
  r.u[1] = (unsigned)f2bf(a[2]) | ((unsigned)f2bf(a[3]) << 16);
  r.u[2] = (unsigned)f2bf(b[0]) | ((unsigned)f2bf(b[1]) << 16);
  r.u[3] = (unsigned)f2bf(b[2]) | ((unsigned)f2bf(b[3]) << 16);
  return r.s;
}

// issue the 3 A-frag DMAs for ring index I (I = round, 12..14 = next step 0..2)
#define DMAI(I) { \
    constexpr int mm_ = (I) % 12; \
    constexpr int kfv_ = (mm_ < 8) ? ((mm_ + KOFF) & 7) : mm_; \
    unsigned char* dst_ = ring_w + ((I) % 3) * 3072; \
    dma16(wsrc + (size_t)((     wv)*12 + kfv_)*1024, dst_); \
    dma16(wsrc + (size_t)((16 + wv)*12 + kfv_)*1024, dst_ + 1024); \
    dma16(wsrc + (size_t)((32 + wv)*12 + kfv_)*1024, dst_ + 2048); \
  }

// load x B-frag pair (m=0,1) for k-block KX of step t into xf0..3 (f32)
#define XLD(KX) { \
    const float* xp0_ = feat + (size_t)(row0 + lo)*(TSTEPS*FDIM) + (size_t)t*FDIM + 32*(KX) + 8*hi; \
    const float* xp1_ = xp0_ + (size_t)16*(TSTEPS*FDIM); \
    xf0 = *(const floatx4*)xp0_; xf1 = *(const floatx4*)(xp0_ + 4); \
    xf2 = *(const floatx4*)xp1_; xf3 = *(const floatx4*)(xp1_ + 4); \
  }

// one K-round: counted vmcnt wait -> B-frags -> ring A ds_reads -> lgkm0 ->
// issue x-prefetch + DMA(g+3) -> 6 MFMAs
#define RND(G) { \
    constexpr int W_ = ((G) < 8) ? 6 : 3; \
    asm volatile("s_waitcnt vmcnt(%0)" :: "i"(W_) : "memory"); \
    short8 b0, b1; \
    if constexpr ((G) >= 8) { \
      b0 = cvt8(xf0, xf1); \
      b1 = cvt8(xf2, xf3); \
    } else { \
      constexpr int kfh_ = ((G) + KOFF) & 7; \
      b0 = ldsH(sm_h, lo,      kfh_*64 + hi*16); \
      b1 = ldsH(sm_h, 16 + lo, kfh_*64 + hi*16); \
    } \
    const unsigned char* rs_ = ring_r + ((G) % 3) * 3072; \
    short8 a0 = *(const short8*)(rs_); \
    short8 a1 = *(const short8*)(rs_ + 1024); \
    short8 a2 = *(const short8*)(rs_ + 2048); \
    asm volatile("s_waitcnt lgkmcnt(0)" ::: "memory"); \
    if constexpr ((G) >= 7 && (G) < 11) { XLD((G) - 7) } \
    DMAI((G) + 3) \
    ar[0] = MFMA(a0, b0, ar[0]); ar[1] = MFMA(a0, b1, ar[1]); \
    az[0] = MFMA(a1, b0, az[0]); az[1] = MFMA(a1, b1, az[1]); \
    if constexpr ((G) < 8) { \
      anh[0] = MFMA(a2, b0, anh[0]); anh[1] = MFMA(a2, b1, anh[1]); \
    } else { \
      anx[0] = MFMA(a2, b0, anx[0]); anx[1] = MFMA(a2, b1, anx[1]); \
    } \
  }

// ---------------- main fused kernel ----------------
template<int KOFF>
__device__ __forceinline__ void gru_body(
    const float* __restrict__ feat, const unsigned short* __restrict__ warr,
    const float* __restrict__ b_ih, const float* __restrict__ b_hh,
    const float* __restrict__ w_pi, const float* __restrict__ b_pi,
    const float* __restrict__ w_vf, const float* __restrict__ b_vf,
    float* __restrict__ out, unsigned char* smem){

  const int tid  = threadIdx.x;
  const int wv   = tid >> 6;              // 0..15 -> owns gate-col frags wv, 16+wv, 32+wv
  const int lane = tid & 63;
  const int lo   = lane & 15, hi = lane >> 4;
  const int row0 = blockIdx.x * MROWS;
  const int cb   = 16*wv + 4*hi;          // gate/h col base for this lane

  unsigned char* sm_h  = smem;                          // 16 KB [32][256] bf16 swizzled
  unsigned char* ring  = smem + 16384 + wv*9216;        // 3 slots x 3 KB per wave
  const unsigned char* ring_r = ring + lane*16;
  unsigned char*       ring_w = ring;                   // uniform; HW adds lane*16
  const unsigned char* wsrc   = (const unsigned char*)warr + lane*16;

  // ---- bias -> registers (float4 loads, one-time)
  floatx4 vr = *(const floatx4*)(b_ih + cb)       + *(const floatx4*)(b_hh + cb);
  floatx4 vz = *(const floatx4*)(b_ih + 256 + cb) + *(const floatx4*)(b_hh + 256 + cb);
  floatx4 vx = *(const floatx4*)(b_ih + 512 + cb);
  floatx4 vh = *(const floatx4*)(b_hh + 512 + cb);

  // ---- zero sm_h (1024 int4 = 16 KB)
  ((int4*)sm_h)[tid] = make_int4(0,0,0,0);

  float hold[2][4] = {};

  __syncthreads();     // full drain OK here (before any ring DMAs)

  // ---- prologue: rings for rounds 0,1,2
  DMAI(0) DMAI(1) DMAI(2)

  #pragma unroll 1
  for (int t = 0; t < TSTEPS; ++t){
    floatx4 ar[2], az[2], anh[2], anx[2];
    ar[0]=vr; ar[1]=vr; az[0]=vz; az[1]=vz;
    anh[0]=vh; anh[1]=vh; anx[0]=vx; anx[1]=vx;
    floatx4 xf0, xf1, xf2, xf3;

    RND(0) RND(1) RND(2) RND(3) RND(4) RND(5) RND(6) RND(7)
    __builtin_amdgcn_s_barrier();   // all sm_h reads done (lgkm drained in R7); no vmcnt drain
    RND(8) RND(9) RND(10) RND(11)

    // ---- lane-local gate math; write h_new (bf16, swizzled, 8B packed)
    #pragma unroll
    for (int m = 0; m < 2; ++m){
      int row = 16*m + lo;
      unsigned q[4];
      #pragma unroll
      for (int j = 0; j < 4; ++j){
        float r  = sigm(ar[m][j]);
        float z  = sigm(az[m][j]);
        float n  = tanh_f(anx[m][j] + r*anh[m][j]);
        float hv = (1.f - z)*n + z*hold[m][j];
        hold[m][j] = hv;
        q[j] = f2bf(hv);
      }
      uint2 pk; pk.x = q[0] | (q[1] << 16); pk.y = q[2] | (q[3] << 16);
      *(uint2*)(sm_h + row*512 + ((cb*2) ^ ((row & 7) << 4))) = pk;
    }
    asm volatile("s_waitcnt lgkmcnt(0)" ::: "memory");
    __builtin_amdgcn_s_barrier();   // h[t+1] visible; next-step ring DMAs stay in flight
  }

  asm volatile("s_waitcnt vmcnt(0)" ::: "memory");   // drain tail DMAs

  // ---- epilogue: leaky(h_last) -> sm_h (bf16)
  #pragma unroll
  for (int m = 0; m < 2; ++m){
    int row = 16*m + lo;
    unsigned q[4];
    #pragma unroll
    for (int j = 0; j < 4; ++j){
      float v = hold[m][j];
      v = (v >= 0.f) ? v : 0.01f*v;
      q[j] = f2bf(v);
    }
    uint2 pk; pk.x = q[0] | (q[1] << 16); pk.y = q[2] | (q[3] << 16);
    *(uint2*)(sm_h + row*512 + ((cb*2) ^ ((row & 7) << 4))) = pk;
  }
  asm volatile("s_waitcnt lgkmcnt(0)" ::: "memory");
  __builtin_amdgcn_s_barrier();

  // ---- heads: 16 waves = 2 heads x 4 out-frags x 2 row-frags
  const int head = wv >> 3;
  const int mfo  = (wv >> 1) & 3;
  const int rh   = wv & 1;
  const float* wh = head ? w_vf : w_pi;
  const float* bh = head ? b_vf : b_pi;
  floatx4 acc = {0.f,0.f,0.f,0.f};
  #pragma unroll
  for (int kf = 0; kf < 8; ++kf){
    const float* ap = wh + (size_t)(16*mfo + lo)*HDIM + 32*kf + 8*hi;
    floatx4 av0 = *(const floatx4*)ap;
    floatx4 av1 = *(const floatx4*)(ap + 4);
    short8 a;
    a[0]=(short)f2bf(av0[0]); a[1]=(short)f2bf(av0[1]); a[2]=(short)f2bf(av0[2]); a[3]=(short)f2bf(av0[3]);
    a[4]=(short)f2bf(av1[0]); a[5]=(short)f2bf(av1[1]); a[6]=(short)f2bf(av1[2]); a[7]=(short)f2bf(av1[3]);
    short8 b = ldsH(sm_h, 16*rh + lo, kf*64 + hi*16);
    acc = MFMA(a, b, acc);
  }
  const size_t outoff = (size_t)head * ((size_t)BATCH * ODIM);
  {
    int grow = row0 + 16*rh + lo;
    #pragma unroll
    for (int j = 0; j < 4; ++j){
      int od = 16*mfo + 4*hi + j;
      float v = acc[j] + bh[od];
      v = (v >= 0.f) ? v : 0.01f*v;
      out[outoff + (size_t)grow*ODIM + od] = v;
    }
  }
}

__global__ __launch_bounds__(NTHR, 4)
void gru_fused(const float* __restrict__ feat, const unsigned short* __restrict__ warr,
               const float* __restrict__ b_ih, const float* __restrict__ b_hh,
               const float* __restrict__ w_pi, const float* __restrict__ b_pi,
               const float* __restrict__ w_vf, const float* __restrict__ b_vf,
               float* __restrict__ out){
  extern __shared__ __align__(16) unsigned char smem[];
  if (blockIdx.x & 1)
    gru_body<4>(feat, warr, b_ih, b_hh, w_pi, b_pi, w_vf, b_vf, out, smem);
  else
    gru_body<0>(feat, warr, b_ih, b_hh, w_pi, b_pi, w_vf, b_vf, out, smem);
}

extern "C" void kernel_launch(void* const* d_in, const int* in_sizes, int n_in,
                              void* d_out, int out_size, void* d_ws, size_t ws_size,
                              hipStream_t stream){
  const float* feat = (const float*)d_in[0];
  const float* w_ih = (const float*)d_in[1];
  const float* w_hh = (const float*)d_in[2];
  const float* b_ih = (const float*)d_in[3];
  const float* b_hh = (const float*)d_in[4];
  const float* w_pi = (const float*)d_in[5];
  const float* b_pi = (const float*)d_in[6];
  const float* w_vf = (const float*)d_in[7];
  const float* b_vf = (const float*)d_in[8];

  unsigned short* warr = (unsigned short*)d_ws;   // 589824 B

  hipFuncSetAttribute((const void*)gru_fused,
                      hipFuncAttributeMaxDynamicSharedMemorySize, SMEM_BYTES);

  prep_weights<<<144, 256, 0, stream>>>(w_ih, w_hh, warr);
  gru_fused<<<NBLK, NTHR, SMEM_BYTES, stream>>>(feat, warr, b_ih, b_hh,
                                                w_pi, b_pi, w_vf, b_vf, (float*)d_out);
}